// Round 5
// baseline (143.327 us; speedup 1.0000x reference)
//
#include <hip/hip_runtime.h>

#define TT 200
#define FF 32
#define HH 50
#define MROWS 16     // batch rows per block
#define PITCH 68     // u32 pitch of h LDS rows

typedef __attribute__((ext_vector_type(8))) short short8;   // 8 bf16 = 4 VGPR
typedef __attribute__((ext_vector_type(4))) float f32x4;
typedef __attribute__((ext_vector_type(4))) unsigned int uint32x4;

__device__ __forceinline__ unsigned short f2bf_rne(float f) {
    unsigned u = __float_as_uint(f);
    unsigned r = u + 0x7fffu + ((u >> 16) & 1u);
    return (unsigned short)(r >> 16);
}
__device__ __forceinline__ float fast_tanh(float x) {
    float e = __expf(2.0f * x);
    return 1.0f - __fdividef(2.0f, e + 1.0f);
}
__device__ __forceinline__ float trunc_hi(float v) {
    return __uint_as_float(__float_as_uint(v) & 0xffff0000u);
}
__device__ __forceinline__ f32x4 mfma16(short8 a, short8 b, f32x4 c) {
    return __builtin_amdgcn_mfma_f32_16x16x32_bf16(a, b, c, 0, 0, 0);
}

// Split fp32 column-slice of M[kdim x 50] into bf16 hi/lo B-frags.
// Layout (validated r4): lane(r,g) elem e -> B[k=kbase+8g+e][col=c].
__device__ __forceinline__ void build_bfrag(const float* __restrict__ M, int kbase,
                                            int kmax, int c, bool cv, int g,
                                            short8& hi, short8& lo) {
    unsigned ph[4], pl[4];
#pragma unroll
    for (int p = 0; p < 4; ++p) {
        const int k0 = kbase + 8 * g + 2 * p, k1 = k0 + 1;
        float v0 = (cv && k0 < kmax) ? M[k0 * HH + c] : 0.0f;
        float v1 = (cv && k1 < kmax) ? M[k1 * HH + c] : 0.0f;
        unsigned short h0 = f2bf_rne(v0), h1 = f2bf_rne(v1);
        ph[p] = ((unsigned)h1 << 16) | h0;
        float r0 = v0 - __uint_as_float((unsigned)h0 << 16);
        float r1 = v1 - __uint_as_float((unsigned)h1 << 16);
        unsigned short l0 = f2bf_rne(r0), l1 = f2bf_rne(r1);
        pl[p] = ((unsigned)l1 << 16) | l0;
    }
    uint32x4 h4 = {ph[0], ph[1], ph[2], ph[3]};
    uint32x4 l4 = {pl[0], pl[1], pl[2], pl[3]};
    hi = __builtin_bit_cast(short8, h4);
    lo = __builtin_bit_cast(short8, l4);
}

// Truncation-split 8 fp32 -> bf16 hi/lo A-frags.
__device__ __forceinline__ void split8(float4 a, float4 b, short8& hi, short8& lo) {
    float v[8] = {a.x, a.y, a.z, a.w, b.x, b.y, b.z, b.w};
    unsigned ph[4], pl[4];
#pragma unroll
    for (int p = 0; p < 4; ++p) {
        unsigned u0 = __float_as_uint(v[2 * p]);
        unsigned u1 = __float_as_uint(v[2 * p + 1]);
        ph[p] = __builtin_amdgcn_perm(u1, u0, 0x07060302u);
        float r0 = v[2 * p]     - __uint_as_float(u0 & 0xffff0000u);
        float r1 = v[2 * p + 1] - __uint_as_float(u1 & 0xffff0000u);
        pl[p] = __builtin_amdgcn_perm(__float_as_uint(r1), __float_as_uint(r0), 0x07060302u);
    }
    uint32x4 h4 = {ph[0], ph[1], ph[2], ph[3]};
    uint32x4 l4 = {pl[0], pl[1], pl[2], pl[3]};
    hi = __builtin_bit_cast(short8, h4);
    lo = __builtin_bit_cast(short8, l4);
}

// Unpack 8 LDS-packed h words (lo16=hh, hi16=hl residual) into A-frags.
__device__ __forceinline__ void unpack8(uint32x4 p0, uint32x4 p1, short8& hh, short8& hl) {
    unsigned ph[4], pl[4];
    ph[0] = __builtin_amdgcn_perm(p0[1], p0[0], 0x05040100u);
    ph[1] = __builtin_amdgcn_perm(p0[3], p0[2], 0x05040100u);
    ph[2] = __builtin_amdgcn_perm(p1[1], p1[0], 0x05040100u);
    ph[3] = __builtin_amdgcn_perm(p1[3], p1[2], 0x05040100u);
    pl[0] = __builtin_amdgcn_perm(p0[1], p0[0], 0x07060302u);
    pl[1] = __builtin_amdgcn_perm(p0[3], p0[2], 0x07060302u);
    pl[2] = __builtin_amdgcn_perm(p1[1], p1[0], 0x07060302u);
    pl[3] = __builtin_amdgcn_perm(p1[3], p1[2], 0x07060302u);
    uint32x4 h4 = {ph[0], ph[1], ph[2], ph[3]};
    uint32x4 l4 = {pl[0], pl[1], pl[2], pl[3]};
    hh = __builtin_bit_cast(short8, h4);
    hl = __builtin_bit_cast(short8, l4);
}

// Block = 16 rows, 2 waves; wave w owns cols 32w..32w+31 (2 MFMA N-tiles).
// Step t: tot = xacc(precomputed) + h_t@U (2 indep 3-chains per tile);
// tanh; pack hi|lo; publish to LDS. x_{t+1}@W computed into nxacc during
// step t (off critical path). Barrier is raw s_barrier + lgkmcnt(0) ONLY —
// __syncthreads would drain vmcnt(0), serializing the x prefetch (r4's
// 1470cyc/step mystery term).
__global__
__attribute__((amdgpu_flat_work_group_size(128, 128)))
__attribute__((amdgpu_waves_per_eu(1, 1)))
void rnn_mfma(const float* __restrict__ x, const float* __restrict__ W,
              const float* __restrict__ U, const float* __restrict__ b,
              const float* __restrict__ Wd, const float* __restrict__ bd,
              float* __restrict__ out)
{
    __shared__ unsigned int hbuf[2][MROWS][PITCH];
    __shared__ float headbuf[2][MROWS];

    const int tid = threadIdx.x;
    const int w = tid >> 6;
    const int l = tid & 63;
    const int r = l & 15;
    const int g = l >> 4;
    const int rb = blockIdx.x * MROWS;

    const int c0 = 32 * w + r, c1 = c0 + 16;
    const bool cv0 = (c0 < HH), cv1 = (c1 < HH);
    short8 Whi0, Wlo0, Whi1, Wlo1;
    build_bfrag(W, 0, FF, c0, cv0, g, Whi0, Wlo0);
    build_bfrag(W, 0, FF, c1, cv1, g, Whi1, Wlo1);
    short8 Uhi00, Ulo00, Uhi01, Ulo01, Uhi10, Ulo10, Uhi11, Ulo11;
    build_bfrag(U, 0,  HH, c0, cv0, g, Uhi00, Ulo00);
    build_bfrag(U, 32, HH, c0, cv0, g, Uhi01, Ulo01);
    build_bfrag(U, 0,  HH, c1, cv1, g, Uhi10, Ulo10);
    build_bfrag(U, 32, HH, c1, cv1, g, Uhi11, Ulo11);
    const float bias0 = cv0 ? b[c0] : 0.0f;
    const float bias1 = cv1 ? b[c1] : 0.0f;
    const float wd0 = cv0 ? Wd[c0] : 0.0f;
    const float wd1 = cv1 ? Wd[c1] : 0.0f;

    const float* xrow = x + ((size_t)(rb + r) * TT) * FF + 8 * g;

    // prologue: xacc = bias + x_0 @ W
    f32x4 xacc0 = {bias0, bias0, bias0, bias0};
    f32x4 xacc1 = {bias1, bias1, bias1, bias1};
    {
        float4 a = *(const float4*)(xrow);
        float4 bb = *(const float4*)(xrow + 4);
        short8 hi, lo;
        split8(a, bb, hi, lo);
        xacc0 = mfma16(hi, Whi0, xacc0); xacc0 = mfma16(lo, Whi0, xacc0); xacc0 = mfma16(hi, Wlo0, xacc0);
        xacc1 = mfma16(hi, Whi1, xacc1); xacc1 = mfma16(lo, Whi1, xacc1); xacc1 = mfma16(hi, Wlo1, xacc1);
    }
    // x prefetch pairs: A holds x_1, B holds x_2 (consumed at t even/odd)
    float4 pa0 = *(const float4*)(xrow + FF),     pa1 = *(const float4*)(xrow + FF + 4);
    float4 pb0 = *(const float4*)(xrow + 2 * FF), pb1 = *(const float4*)(xrow + 2 * FF + 4);

    float hf0[4], hf1[4];

    auto step = [&](int t, float4& qa, float4& qb) {
        // h_t LDS reads issue first (deepest latency on the path)
        uint32x4 p0a, p1a, p0b, p1b;
        if (t > 0) {
            const int buf = t & 1;
            const unsigned* base0 = &hbuf[buf][r][8 * g];
            const unsigned* base1 = &hbuf[buf][r][32 + 8 * g];
            p0a = *(const uint32x4*)(base0);
            p1a = *(const uint32x4*)(base0 + 4);
            p0b = *(const uint32x4*)(base1);
            p1b = *(const uint32x4*)(base1 + 4);
        }

        // x_{t+1}@W into nxacc (independent of h — fills LDS-read latency)
        short8 nxhi, nxlo;
        split8(qa, qb, nxhi, nxlo);
        int tn = t + 3; if (tn > TT - 1) tn = TT - 1;
        qa = *(const float4*)(xrow + (size_t)tn * FF);
        qb = *(const float4*)(xrow + (size_t)tn * FF + 4);
        f32x4 nx0 = {bias0, bias0, bias0, bias0};
        f32x4 nx1 = {bias1, bias1, bias1, bias1};
        nx0 = mfma16(nxhi, Whi0, nx0); nx0 = mfma16(nxlo, Whi0, nx0); nx0 = mfma16(nxhi, Wlo0, nx0);
        nx1 = mfma16(nxhi, Whi1, nx1); nx1 = mfma16(nxlo, Whi1, nx1); nx1 = mfma16(nxhi, Wlo1, nx1);

        f32x4 tot0 = xacc0, tot1 = xacc1;
        if (t > 0) {
            short8 hh0, hl0, hh1, hl1;
            unpack8(p0a, p1a, hh0, hl0);
            unpack8(p0b, p1b, hh1, hl1);
            // 4 independent 3-chains (2 per output tile), xacc as C-in
            f32x4 ca = mfma16(hh0, Uhi00, xacc0);
            f32x4 da = mfma16(hh0, Uhi10, xacc1);
            f32x4 cb = {0.0f, 0.0f, 0.0f, 0.0f};
            f32x4 db = {0.0f, 0.0f, 0.0f, 0.0f};
            cb = mfma16(hh1, Uhi01, cb);
            db = mfma16(hh1, Uhi11, db);
            ca = mfma16(hl0, Uhi00, ca);
            da = mfma16(hl0, Uhi10, da);
            cb = mfma16(hl1, Uhi01, cb);
            db = mfma16(hl1, Uhi11, db);
            ca = mfma16(hh0, Ulo00, ca);
            da = mfma16(hh0, Ulo10, da);
            cb = mfma16(hh1, Ulo01, cb);
            db = mfma16(hh1, Ulo11, db);
            tot0 = ca + cb;
            tot1 = da + db;
        }

        // tanh + pack (hl16<<16 | hh16) + publish h_{t+1}
        const int nbuf = (t + 1) & 1;
        unsigned* wptr = &hbuf[nbuf][4 * g][32 * w + r];
#pragma unroll
        for (int i = 0; i < 4; ++i) {
            float h0 = fast_tanh(tot0[i]);
            float h1 = fast_tanh(tot1[i]);
            hf0[i] = h0; hf1[i] = h1;
            float r0 = h0 - trunc_hi(h0);
            float r1 = h1 - trunc_hi(h1);
            wptr[i * PITCH]      = __builtin_amdgcn_perm(__float_as_uint(r0), __float_as_uint(h0), 0x07060302u);
            wptr[i * PITCH + 16] = __builtin_amdgcn_perm(__float_as_uint(r1), __float_as_uint(h1), 0x07060302u);
        }
        xacc0 = nx0; xacc1 = nx1;
        // LDS-only drain + barrier: x global loads stay in flight
        asm volatile("s_waitcnt lgkmcnt(0)\n\ts_barrier" ::: "memory");
    };

    for (int t = 0; t < TT; t += 2) {
        step(t,     pa0, pa1);
        step(t + 1, pb0, pb1);
    }

    // head: out[row] = relu(sum_j h[row][j]*Wd[j] + bd)
    float pp[4];
#pragma unroll
    for (int i = 0; i < 4; ++i) {
        float p = hf0[i] * wd0 + hf1[i] * wd1;
        p += __shfl_xor(p, 1);
        p += __shfl_xor(p, 2);
        p += __shfl_xor(p, 4);
        p += __shfl_xor(p, 8);
        pp[i] = p;
    }
    if (r == 0) {
#pragma unroll
        for (int i = 0; i < 4; ++i) headbuf[w][4 * g + i] = pp[i];
    }
    __syncthreads();
    if (w == 0 && l < MROWS)
        out[rb + l] = fmaxf(headbuf[0][l] + headbuf[1][l] + bd[0], 0.0f);
}

extern "C" void kernel_launch(void* const* d_in, const int* in_sizes, int n_in,
                              void* d_out, int out_size, void* d_ws, size_t ws_size,
                              hipStream_t stream) {
    const float* x  = (const float*)d_in[0];
    const float* W  = (const float*)d_in[1];
    const float* U  = (const float*)d_in[2];
    const float* b  = (const float*)d_in[3];
    const float* Wd = (const float*)d_in[4];
    const float* bd = (const float*)d_in[5];
    float* out = (float*)d_out;
    const int B = out_size;                       // 4096
    dim3 grid(B / MROWS), block(128);             // 256 blocks, 2 waves each
    hipLaunchKernelGGL(rnn_mfma, grid, block, 0, stream,
                       x, W, U, b, Wd, bd, out);
    (void)d_ws; (void)ws_size; (void)in_sizes; (void)n_in;
}